// Round 14
// baseline (32.407 us; speedup 1.0000x reference)
//
#include <hip/hip_runtime.h>
#include <math.h>

#define NROWS 8192
#define NC 10
#define LOG2E_F 1.4426950408889634f

typedef short bf16x8 __attribute__((ext_vector_type(8)));   // MFMA a/b frag
typedef float f32x4 __attribute__((ext_vector_type(4)));    // MFMA c/d frag
typedef unsigned short u16;
typedef unsigned int u32;

#if __has_builtin(__builtin_amdgcn_exp2f)
#define EXP2F(x) __builtin_amdgcn_exp2f(x)
#else
#define EXP2F(x) exp2f(x)
#endif

__device__ __forceinline__ float fast_log2(float x) {       // v_log_f32 = log2
    float r; asm("v_log_f32 %0, %1" : "=v"(r) : "v"(x)); return r;
}

// lgamma(x) for x in [1, 11.01]: Stirling at y=x+8 (2 correction terms)
// minus ln(x(x+1)...(x+7)). abs err < 1e-5 over the range.
__device__ __forceinline__ float lgamma_fast(float x) {
    const float LN2 = 0.6931471805599453f;
    float p = x * (x + 1.f) * (x + 2.f) * (x + 3.f) *
              (x + 4.f) * (x + 5.f) * (x + 6.f) * (x + 7.f);
    float y = x + 8.f;
    float lny = fast_log2(y) * LN2;
    float lnp = fast_log2(p) * LN2;
    float r = 1.f / y;
    return fmaf(y - 0.5f, lny, -y) + 0.91893853320467274f   // 0.5*ln(2*pi)
           + r * (1.f / 12.f) - (r * r * r) * (1.f / 360.f) - lnp;
}

__device__ __forceinline__ u16 f2bf(float x) {              // RNE f32->bf16
    u32 u = __float_as_uint(x);
    return (u16)((u + 0x7FFFu + ((u >> 16) & 1u)) >> 16);
}
__device__ __forceinline__ float bf2f(u16 b) { return __uint_as_float(((u32)b) << 16); }
__device__ __forceinline__ u32 cvtpk_bf16(float lo, float hi) {
    u32 r; asm("v_cvt_pk_bf16_f32 %0, %1, %2" : "=v"(r) : "v"(lo), "v"(hi)); return r;
}

union U8 { u16 s[8]; int4 v; };

// ws layout (f32 units):
//   P    : [N][12] = {f0..f9, -B2, label_bits}      0   .. 12N
//   L10  : [N][10]                                  12N .. 22N
//   AFP  : [512 jt16][64][8] bf16                   22N .. 38N
//   BLP  : [512 it16][64][8] bf16                   38N .. 54N
//   OHP  : [256 jt32][64][8] bf16                   54N .. 62N
//   bsum : [128]                                    62N

// ---------------- Kernel 1: prep + pack (128 blocks x 64 threads) -----------
// (verbatim from round 13 — verified)
__global__ __launch_bounds__(64) void kde_prep_pack(const float* __restrict__ logits,
                                                    const int* __restrict__ labels,
                                                    float* __restrict__ P,
                                                    float* __restrict__ L10,
                                                    u16* __restrict__ AFP,
                                                    u16* __restrict__ BLP,
                                                    u16* __restrict__ OHP) {
    __shared__ float sF[64][NC];
    __shared__ float sL[64][NC];
    __shared__ float sB2[64];
    __shared__ int sLab[64];
    const int tid = threadIdx.x, bx = blockIdx.x;
    const int i = bx * 64 + tid;

    float l[NC];
#pragma unroll
    for (int c = 0; c < NC; ++c) l[c] = logits[(size_t)i * NC + c];
    float m = l[0];
#pragma unroll
    for (int c = 1; c < NC; ++c) m = fmaxf(m, l[c]);
    float e[NC];
    float sum = 0.f;
#pragma unroll
    for (int c = 0; c < NC; ++c) {
        e[c] = EXP2F((l[c] - m) * LOG2E_F);
        sum += e[c];
    }
    float inv = 1.f / sum;
    float lg2sum = fast_log2(sum);
    float lg = 0.f;
#pragma unroll
    for (int c = 0; c < NC; ++c) {
        float f = e[c] * inv;
        P[(size_t)i * 12 + c] = f;
        sF[tid][c] = f;
        // L10 = 10*log2(f) analytically (f >= ~2e-4 here; eps irrelevant)
        float L = 10.f * ((l[c] - m) * LOG2E_F - lg2sum);
        L10[(size_t)i * NC + c] = L;
        sL[tid][c] = L;
        lg += lgamma_fast(fmaf(10.f, f, 1.f));
    }
    // sum(alphas) == 1/h + C == 20 exactly -> lgamma(20) = ln(19!) constant
    float b2 = (lg - 39.339884187199495f) * LOG2E_F;
    P[(size_t)i * 12 + 10] = -b2;
    sB2[tid] = -b2;
    int lab = labels[i];
    P[(size_t)i * 12 + 11] = __int_as_float(lab);
    sLab[tid] = lab;
    __syncthreads();

    const int lc = tid & 15, h = tid >> 4;
    // ---- AFP: 4 jt16 tiles (j side: Fhi/Flo, -B2 hi/lo) ----
#pragma unroll
    for (int t = 0; t < 4; ++t) {
        const int jl = t * 16 + lc;
        const float* f = sF[jl];
        u16 FH[10], FL[10];
#pragma unroll
        for (int c = 0; c < 10; ++c) {
            FH[c] = f2bf(f[c]);
            FL[c] = f2bf(f[c] - bf2f(FH[c]));
        }
        float nb2 = sB2[jl];
        u16 bh = f2bf(nb2);
        u16 blo = f2bf(nb2 - bf2f(bh));
        U8 o;
        if (h == 0) {        // k=0..7   : Fhi[0..7]
            o.s[0]=FH[0]; o.s[1]=FH[1]; o.s[2]=FH[2]; o.s[3]=FH[3];
            o.s[4]=FH[4]; o.s[5]=FH[5]; o.s[6]=FH[6]; o.s[7]=FH[7];
        } else if (h == 1) { // k=8..15 : Fhi[8,9], Flo[0..5]
            o.s[0]=FH[8]; o.s[1]=FH[9]; o.s[2]=FL[0]; o.s[3]=FL[1];
            o.s[4]=FL[2]; o.s[5]=FL[3]; o.s[6]=FL[4]; o.s[7]=FL[5];
        } else if (h == 2) { // k=16..23: Flo[6..9], Fhi[0..3]
            o.s[0]=FL[6]; o.s[1]=FL[7]; o.s[2]=FL[8]; o.s[3]=FL[9];
            o.s[4]=FH[0]; o.s[5]=FH[1]; o.s[6]=FH[2]; o.s[7]=FH[3];
        } else {             // k=24..31: Fhi[4..9], -B2hi, -B2lo
            o.s[0]=FH[4]; o.s[1]=FH[5]; o.s[2]=FH[6]; o.s[3]=FH[7];
            o.s[4]=FH[8]; o.s[5]=FH[9]; o.s[6]=bh;    o.s[7]=blo;
        }
        *(int4*)&AFP[((size_t)(bx * 4 + t) * 64 + tid) * 8] = o.v;
    }
    // ---- BLP: 4 it16 tiles (i side: L10hi/lo, ones) ----
#pragma unroll
    for (int t = 0; t < 4; ++t) {
        const int il = t * 16 + lc;
        u16 LH[10], LL[10];
#pragma unroll
        for (int c = 0; c < 10; ++c) {
            float L = sL[il][c];
            LH[c] = f2bf(L);
            LL[c] = f2bf(L - bf2f(LH[c]));
        }
        const u16 ONE = 0x3F80;
        U8 o;
        if (h == 0) {        // k=0..7   : L10hi[0..7]
            o.s[0]=LH[0]; o.s[1]=LH[1]; o.s[2]=LH[2]; o.s[3]=LH[3];
            o.s[4]=LH[4]; o.s[5]=LH[5]; o.s[6]=LH[6]; o.s[7]=LH[7];
        } else if (h == 1) { // k=8..15 : L10hi[8,9], L10hi[0..5]
            o.s[0]=LH[8]; o.s[1]=LH[9]; o.s[2]=LH[0]; o.s[3]=LH[1];
            o.s[4]=LH[2]; o.s[5]=LH[3]; o.s[6]=LH[4]; o.s[7]=LH[5];
        } else if (h == 2) { // k=16..23: L10hi[6..9], L10lo[0..3]
            o.s[0]=LH[6]; o.s[1]=LH[7]; o.s[2]=LH[8]; o.s[3]=LH[9];
            o.s[4]=LL[0]; o.s[5]=LL[1]; o.s[6]=LL[2]; o.s[7]=LL[3];
        } else {             // k=24..31: L10lo[4..9], 1, 1
            o.s[0]=LL[4]; o.s[1]=LL[5]; o.s[2]=LL[6]; o.s[3]=LL[7];
            o.s[4]=LL[8]; o.s[5]=LL[9]; o.s[6]=ONE;   o.s[7]=ONE;
        }
        *(int4*)&BLP[((size_t)(bx * 4 + t) * 64 + tid) * 8] = o.v;
    }
    // ---- OHP: 2 jt32 tiles (onehot + den-ones col 10) ----
#pragma unroll
    for (int t = 0; t < 2; ++t) {
        U8 o;
#pragma unroll
        for (int e = 0; e < 8; ++e) {
            int jl = t * 32 + ((e >> 2) << 4) + h * 4 + (e & 3);   // j_log(h,e)
            int lj = sLab[jl];
            o.s[e] = (lc == lj || lc == 10) ? (u16)0x3F80 : (u16)0;
        }
        *(int4*)&OHP[((size_t)(bx * 2 + t) * 64 + tid) * 8] = o.v;
    }
}

// ---- Kernel 2: MFMA main, full-j per block, 64 i-rows (128 x 1024) ---------
__global__ __launch_bounds__(1024) void kde_main(const u16* __restrict__ AFP_,
                                                 const u16* __restrict__ BLP_,
                                                 const u16* __restrict__ OHP_,
                                                 const float* __restrict__ P,
                                                 const float* __restrict__ L10,
                                                 float* __restrict__ bsum) {
    const bf16x8* AFP = (const bf16x8*)AFP_;
    const bf16x8* BLP = (const bf16x8*)BLP_;
    const bf16x8* OHP = (const bf16x8*)OHP_;
    const int tid = threadIdx.x, w = tid >> 6, l = tid & 63;   // 16 waves
    const int ib = blockIdx.x;          // 64 i-rows per block: i = ib*64 + [0,64)

    bf16x8 bl[4];                       // block's 4 it16 B-frags (same for all waves)
#pragma unroll
    for (int t = 0; t < 4; ++t) bl[t] = BLP[(size_t)(ib * 4 + t) * 64 + l];

    const f32x4 z = {0.f, 0.f, 0.f, 0.f};
    f32x4 acc[4] = {z, z, z, z};

    // wave w covers jt in [w*16, w*16+16) -> 16 waves cover all 256 jt32 tiles
    for (int jt = w * 16; jt < w * 16 + 16; ++jt) {
        bf16x8 af0 = AFP[(size_t)(2 * jt) * 64 + l];
        bf16x8 af1 = AFP[(size_t)(2 * jt + 1) * 64 + l];
        bf16x8 oh  = OHP[(size_t)jt * 64 + l];
#pragma unroll
        for (int t = 0; t < 4; ++t) {
            f32x4 s0 = __builtin_amdgcn_mfma_f32_16x16x32_bf16(af0, bl[t], z, 0, 0, 0);
            f32x4 s1 = __builtin_amdgcn_mfma_f32_16x16x32_bf16(af1, bl[t], z, 0, 0, 0);
            union { bf16x8 v; u32 u[4]; } kf;
            kf.u[0] = cvtpk_bf16(EXP2F(s0.x), EXP2F(s0.y));
            kf.u[1] = cvtpk_bf16(EXP2F(s0.z), EXP2F(s0.w));
            kf.u[2] = cvtpk_bf16(EXP2F(s1.x), EXP2F(s1.y));
            kf.u[3] = cvtpk_bf16(EXP2F(s1.z), EXP2F(s1.w));
            acc[t] = __builtin_amdgcn_mfma_f32_16x16x32_bf16(kf.v, oh, acc[t], 0, 0, 0);
        }
    }

    // ---- cross-wave reduction (w-ascending = j-ascending left fold) ----
    __shared__ f32x4 sRed[16][4][64];   // 64 KB
#pragma unroll
    for (int t = 0; t < 4; ++t) sRed[w][t][l] = acc[t];
    __syncthreads();

    __shared__ float sC[4][16][12];     // [tile][row][class] (pad 12)
    if (w == 0) {
        f32x4 t0 = sRed[0][0][l];
        f32x4 t1 = sRed[0][1][l];
        f32x4 t2 = sRed[0][2][l];
        f32x4 t3 = sRed[0][3][l];
#pragma unroll
        for (int ww = 1; ww < 16; ++ww) {
            t0 += sRed[ww][0][l]; t1 += sRed[ww][1][l];
            t2 += sRed[ww][2][l]; t3 += sRed[ww][3][l];
        }
        const int c = l & 15, h = l >> 4;   // verified C/D map: col=lane&15, row=(lane>>4)*4+reg
        if (c < 11) {
#pragma unroll
            for (int reg = 0; reg < 4; ++reg) {
                sC[0][h * 4 + reg][c] = t0[reg];
                sC[1][h * 4 + reg][c] = t1[reg];
                sC[2][h * 4 + reg][c] = t2[reg];
                sC[3][h * 4 + reg][c] = t3[reg];
            }
        }
    }
    __syncthreads();

    __shared__ float sPer[64];
    if (tid < 64) {
        const int i = ib * 64 + tid;
        float a11[11];
#pragma unroll
        for (int cc = 0; cc < 11; ++cc) a11[cc] = sC[tid >> 4][tid & 15][cc];

        // self-kernel: reconstruct the SAME bf16 operand values as the pack,
        // sum products in fixed order, exp2 + bf16-round like the PV input.
        const float* f = &P[(size_t)i * 12];
        float FH[10], FL[10], LH[10], LL[10];
#pragma unroll
        for (int cc = 0; cc < 10; ++cc) {
            u16 a = f2bf(f[cc]);           FH[cc] = bf2f(a);
            u16 b = f2bf(f[cc] - FH[cc]);  FL[cc] = bf2f(b);
            float L = L10[(size_t)i * NC + cc];
            u16 x = f2bf(L);               LH[cc] = bf2f(x);
            u16 y = f2bf(L - LH[cc]);      LL[cc] = bf2f(y);
        }
        float nb2 = f[10];
        float BH = bf2f(f2bf(nb2));
        float BL = bf2f(f2bf(nb2 - BH));
        float S = 0.f;
#pragma unroll
        for (int cc = 0; cc < 10; ++cc) S += FH[cc] * LH[cc];
#pragma unroll
        for (int cc = 0; cc < 10; ++cc) S += FL[cc] * LH[cc];
#pragma unroll
        for (int cc = 0; cc < 10; ++cc) S += FH[cc] * LL[cc];
        S += BH; S += BL;
        float self = bf2f((u16)(cvtpk_bf16(EXP2F(S), 0.f) & 0xFFFFu));
        int lab = __float_as_int(f[11]);
        float den = a11[10] - self;
        switch (lab) {
#define CASE(cc) case cc: a11[cc] -= self; break;
            CASE(0) CASE(1) CASE(2) CASE(3) CASE(4)
            CASE(5) CASE(6) CASE(7) CASE(8) CASE(9)
#undef CASE
        }

        den = fmaxf(den, 1e-10f);   // clip(den, EPS_DEN, None)
        float per = 0.f;
#pragma unroll
        for (int cc = 0; cc < NC; ++cc) per += fabsf(a11[cc] / den - f[cc]);
        sPer[tid] = per;
    }
    __syncthreads();
    if (tid == 0) {
        float s = 0.f;
#pragma unroll
        for (int k = 0; k < 64; ++k) s += sPer[k];
        bsum[ib] = s;
    }
}

// ---------------- Kernel 3: final 128-value reduce (1 block) ----------------
__global__ __launch_bounds__(256) void kde_finC(const float* __restrict__ bsum,
                                                float* __restrict__ out) {
    __shared__ float red[256];
    const int t = threadIdx.x;
    red[t] = (t < 128) ? bsum[t] : 0.f;
    __syncthreads();
    for (int off = 128; off > 0; off >>= 1) {
        if (t < off) red[t] += red[t + off];
        __syncthreads();
    }
    if (t == 0) out[0] = red[0] * (1.0f / NROWS);
}

extern "C" void kernel_launch(void* const* d_in, const int* in_sizes, int n_in,
                              void* d_out, int out_size, void* d_ws, size_t ws_size,
                              hipStream_t stream) {
    const float* logits = (const float*)d_in[0];
    const int* labels = (const int*)d_in[1];
    float* out = (float*)d_out;
    float* ws = (float*)d_ws;

    float* P   = ws;                                   // 12N
    float* L10 = ws + 12 * NROWS;                      // 10N
    u16* AFP = (u16*)(ws + 22 * NROWS);                // 16N f32-equiv
    u16* BLP = (u16*)(ws + 38 * NROWS);                // 16N
    u16* OHP = (u16*)(ws + 54 * NROWS);                // 8N
    float* bsum = ws + 62 * NROWS;                     // 128

    kde_prep_pack<<<dim3(NROWS / 64), dim3(64), 0, stream>>>(logits, labels, P, L10,
                                                             AFP, BLP, OHP);
    kde_main<<<dim3(NROWS / 64), dim3(1024), 0, stream>>>(AFP, BLP, OHP, P, L10, bsum);
    kde_finC<<<dim3(1), dim3(256), 0, stream>>>(bsum, out);
}

// Round 15
// 29.922 us; speedup vs baseline: 1.0830x; 1.0830x over previous
//
#include <hip/hip_runtime.h>
#include <math.h>

#define NROWS 8192
#define NC 10
#define LOG2E_F 1.4426950408889634f

typedef short bf16x8 __attribute__((ext_vector_type(8)));   // MFMA a/b frag
typedef float f32x4 __attribute__((ext_vector_type(4)));    // MFMA c/d frag
typedef unsigned short u16;
typedef unsigned int u32;

#if __has_builtin(__builtin_amdgcn_exp2f)
#define EXP2F(x) __builtin_amdgcn_exp2f(x)
#else
#define EXP2F(x) exp2f(x)
#endif

__device__ __forceinline__ float fast_log2(float x) {       // v_log_f32 = log2
    float r; asm("v_log_f32 %0, %1" : "=v"(r) : "v"(x)); return r;
}

// lgamma(x) for x in [1, 11.01]: Stirling at y=x+8 (2 correction terms)
// minus ln(x(x+1)...(x+7)). abs err < 1e-5 over the range.
__device__ __forceinline__ float lgamma_fast(float x) {
    const float LN2 = 0.6931471805599453f;
    float p = x * (x + 1.f) * (x + 2.f) * (x + 3.f) *
              (x + 4.f) * (x + 5.f) * (x + 6.f) * (x + 7.f);
    float y = x + 8.f;
    float lny = fast_log2(y) * LN2;
    float lnp = fast_log2(p) * LN2;
    float r = 1.f / y;
    return fmaf(y - 0.5f, lny, -y) + 0.91893853320467274f   // 0.5*ln(2*pi)
           + r * (1.f / 12.f) - (r * r * r) * (1.f / 360.f) - lnp;
}

__device__ __forceinline__ u16 f2bf(float x) {              // RNE f32->bf16
    u32 u = __float_as_uint(x);
    return (u16)((u + 0x7FFFu + ((u >> 16) & 1u)) >> 16);
}
__device__ __forceinline__ float bf2f(u16 b) { return __uint_as_float(((u32)b) << 16); }
__device__ __forceinline__ u32 cvtpk_bf16(float lo, float hi) {
    u32 r; asm("v_cvt_pk_bf16_f32 %0, %1, %2" : "=v"(r) : "v"(lo), "v"(hi)); return r;
}

union U8 { u16 s[8]; int4 v; };

// ws layout (f32 units):
//   P    : [N][12] = {f0..f9, -B2, label_bits}      0   .. 12N
//   L10  : [N][10]                                  12N .. 22N
//   AFP  : [512 jt16][64][8] bf16                   22N .. 38N
//   BLP  : [512 it16][64][8] bf16                   38N .. 54N
//   OHP  : [256 jt32][64][8] bf16                   54N .. 62N

// ---------------- Kernel 1: prep + pack (128 blocks x 64 threads) -----------
// (verbatim from round 13 — verified)
__global__ __launch_bounds__(64) void kde_prep_pack(const float* __restrict__ logits,
                                                    const int* __restrict__ labels,
                                                    float* __restrict__ P,
                                                    float* __restrict__ L10,
                                                    u16* __restrict__ AFP,
                                                    u16* __restrict__ BLP,
                                                    u16* __restrict__ OHP) {
    __shared__ float sF[64][NC];
    __shared__ float sL[64][NC];
    __shared__ float sB2[64];
    __shared__ int sLab[64];
    const int tid = threadIdx.x, bx = blockIdx.x;
    const int i = bx * 64 + tid;

    float l[NC];
#pragma unroll
    for (int c = 0; c < NC; ++c) l[c] = logits[(size_t)i * NC + c];
    float m = l[0];
#pragma unroll
    for (int c = 1; c < NC; ++c) m = fmaxf(m, l[c]);
    float e[NC];
    float sum = 0.f;
#pragma unroll
    for (int c = 0; c < NC; ++c) {
        e[c] = EXP2F((l[c] - m) * LOG2E_F);
        sum += e[c];
    }
    float inv = 1.f / sum;
    float lg2sum = fast_log2(sum);
    float lg = 0.f;
#pragma unroll
    for (int c = 0; c < NC; ++c) {
        float f = e[c] * inv;
        P[(size_t)i * 12 + c] = f;
        sF[tid][c] = f;
        // L10 = 10*log2(f) analytically (f >= ~2e-4 here; eps irrelevant)
        float L = 10.f * ((l[c] - m) * LOG2E_F - lg2sum);
        L10[(size_t)i * NC + c] = L;
        sL[tid][c] = L;
        lg += lgamma_fast(fmaf(10.f, f, 1.f));
    }
    // sum(alphas) == 1/h + C == 20 exactly -> lgamma(20) = ln(19!) constant
    float b2 = (lg - 39.339884187199495f) * LOG2E_F;
    P[(size_t)i * 12 + 10] = -b2;
    sB2[tid] = -b2;
    int lab = labels[i];
    P[(size_t)i * 12 + 11] = __int_as_float(lab);
    sLab[tid] = lab;
    __syncthreads();

    const int lc = tid & 15, h = tid >> 4;
    // ---- AFP: 4 jt16 tiles (j side: Fhi/Flo, -B2 hi/lo) ----
#pragma unroll
    for (int t = 0; t < 4; ++t) {
        const int jl = t * 16 + lc;
        const float* f = sF[jl];
        u16 FH[10], FL[10];
#pragma unroll
        for (int c = 0; c < 10; ++c) {
            FH[c] = f2bf(f[c]);
            FL[c] = f2bf(f[c] - bf2f(FH[c]));
        }
        float nb2 = sB2[jl];
        u16 bh = f2bf(nb2);
        u16 blo = f2bf(nb2 - bf2f(bh));
        U8 o;
        if (h == 0) {        // k=0..7   : Fhi[0..7]
            o.s[0]=FH[0]; o.s[1]=FH[1]; o.s[2]=FH[2]; o.s[3]=FH[3];
            o.s[4]=FH[4]; o.s[5]=FH[5]; o.s[6]=FH[6]; o.s[7]=FH[7];
        } else if (h == 1) { // k=8..15 : Fhi[8,9], Flo[0..5]
            o.s[0]=FH[8]; o.s[1]=FH[9]; o.s[2]=FL[0]; o.s[3]=FL[1];
            o.s[4]=FL[2]; o.s[5]=FL[3]; o.s[6]=FL[4]; o.s[7]=FL[5];
        } else if (h == 2) { // k=16..23: Flo[6..9], Fhi[0..3]
            o.s[0]=FL[6]; o.s[1]=FL[7]; o.s[2]=FL[8]; o.s[3]=FL[9];
            o.s[4]=FH[0]; o.s[5]=FH[1]; o.s[6]=FH[2]; o.s[7]=FH[3];
        } else {             // k=24..31: Fhi[4..9], -B2hi, -B2lo
            o.s[0]=FH[4]; o.s[1]=FH[5]; o.s[2]=FH[6]; o.s[3]=FH[7];
            o.s[4]=FH[8]; o.s[5]=FH[9]; o.s[6]=bh;    o.s[7]=blo;
        }
        *(int4*)&AFP[((size_t)(bx * 4 + t) * 64 + tid) * 8] = o.v;
    }
    // ---- BLP: 4 it16 tiles (i side: L10hi/lo, ones) ----
#pragma unroll
    for (int t = 0; t < 4; ++t) {
        const int il = t * 16 + lc;
        u16 LH[10], LL[10];
#pragma unroll
        for (int c = 0; c < 10; ++c) {
            float L = sL[il][c];
            LH[c] = f2bf(L);
            LL[c] = f2bf(L - bf2f(LH[c]));
        }
        const u16 ONE = 0x3F80;
        U8 o;
        if (h == 0) {        // k=0..7   : L10hi[0..7]
            o.s[0]=LH[0]; o.s[1]=LH[1]; o.s[2]=LH[2]; o.s[3]=LH[3];
            o.s[4]=LH[4]; o.s[5]=LH[5]; o.s[6]=LH[6]; o.s[7]=LH[7];
        } else if (h == 1) { // k=8..15 : L10hi[8,9], L10hi[0..5]
            o.s[0]=LH[8]; o.s[1]=LH[9]; o.s[2]=LH[0]; o.s[3]=LH[1];
            o.s[4]=LH[2]; o.s[5]=LH[3]; o.s[6]=LH[4]; o.s[7]=LH[5];
        } else if (h == 2) { // k=16..23: L10hi[6..9], L10lo[0..3]
            o.s[0]=LH[6]; o.s[1]=LH[7]; o.s[2]=LH[8]; o.s[3]=LH[9];
            o.s[4]=LL[0]; o.s[5]=LL[1]; o.s[6]=LL[2]; o.s[7]=LL[3];
        } else {             // k=24..31: L10lo[4..9], 1, 1
            o.s[0]=LL[4]; o.s[1]=LL[5]; o.s[2]=LL[6]; o.s[3]=LL[7];
            o.s[4]=LL[8]; o.s[5]=LL[9]; o.s[6]=ONE;   o.s[7]=ONE;
        }
        *(int4*)&BLP[((size_t)(bx * 4 + t) * 64 + tid) * 8] = o.v;
    }
    // ---- OHP: 2 jt32 tiles (onehot + den-ones col 10) ----
#pragma unroll
    for (int t = 0; t < 2; ++t) {
        U8 o;
#pragma unroll
        for (int e = 0; e < 8; ++e) {
            int jl = t * 32 + ((e >> 2) << 4) + h * 4 + (e & 3);   // j_log(h,e)
            int lj = sLab[jl];
            o.s[e] = (lc == lj || lc == 10) ? (u16)0x3F80 : (u16)0;
        }
        *(int4*)&OHP[((size_t)(bx * 2 + t) * 64 + tid) * 8] = o.v;
    }
}

// ---- Kernel 2: MFMA main (round-13 structure, 256 x 1024) + atomic finish ---
__global__ __launch_bounds__(1024) void kde_main(const u16* __restrict__ AFP_,
                                                 const u16* __restrict__ BLP_,
                                                 const u16* __restrict__ OHP_,
                                                 const float* __restrict__ P,
                                                 const float* __restrict__ L10,
                                                 float* __restrict__ out) {
    const bf16x8* AFP = (const bf16x8*)AFP_;
    const bf16x8* BLP = (const bf16x8*)BLP_;
    const bf16x8* OHP = (const bf16x8*)OHP_;
    const int tid = threadIdx.x, w = tid >> 6, l = tid & 63;   // 16 waves
    const int ib = blockIdx.x;          // 32 i-rows per block: i = ib*32 + [0,32)

    bf16x8 bl[2];                       // block's 2 it16 B-frags (same for all waves)
#pragma unroll
    for (int t = 0; t < 2; ++t) bl[t] = BLP[(size_t)(ib * 2 + t) * 64 + l];

    const f32x4 z = {0.f, 0.f, 0.f, 0.f};
    f32x4 acc[2] = {z, z};

    // wave w covers jt in [w*16, w*16+16) -> 16 waves cover all 256 jt32 tiles
    for (int jt = w * 16; jt < w * 16 + 16; ++jt) {
        bf16x8 af0 = AFP[(size_t)(2 * jt) * 64 + l];
        bf16x8 af1 = AFP[(size_t)(2 * jt + 1) * 64 + l];
        bf16x8 oh  = OHP[(size_t)jt * 64 + l];
#pragma unroll
        for (int t = 0; t < 2; ++t) {
            f32x4 s0 = __builtin_amdgcn_mfma_f32_16x16x32_bf16(af0, bl[t], z, 0, 0, 0);
            f32x4 s1 = __builtin_amdgcn_mfma_f32_16x16x32_bf16(af1, bl[t], z, 0, 0, 0);
            union { bf16x8 v; u32 u[4]; } kf;
            kf.u[0] = cvtpk_bf16(EXP2F(s0.x), EXP2F(s0.y));
            kf.u[1] = cvtpk_bf16(EXP2F(s0.z), EXP2F(s0.w));
            kf.u[2] = cvtpk_bf16(EXP2F(s1.x), EXP2F(s1.y));
            kf.u[3] = cvtpk_bf16(EXP2F(s1.z), EXP2F(s1.w));
            acc[t] = __builtin_amdgcn_mfma_f32_16x16x32_bf16(kf.v, oh, acc[t], 0, 0, 0);
        }
    }

    // ---- cross-wave reduction (w-ascending = j-ascending left fold) ----
    __shared__ f32x4 sRed[16][2][64];   // 32 KB
    sRed[w][0][l] = acc[0];
    sRed[w][1][l] = acc[1];
    __syncthreads();

    __shared__ float sC[2][16][12];     // [tile][row][class] (pad 12)
    if (w == 0) {
        f32x4 t0 = sRed[0][0][l];
        f32x4 t1 = sRed[0][1][l];
#pragma unroll
        for (int ww = 1; ww < 16; ++ww) { t0 += sRed[ww][0][l]; t1 += sRed[ww][1][l]; }
        const int c = l & 15, h = l >> 4;   // verified C/D map: col=lane&15, row=(lane>>4)*4+reg
        if (c < 11) {
#pragma unroll
            for (int reg = 0; reg < 4; ++reg) {
                sC[0][h * 4 + reg][c] = t0[reg];
                sC[1][h * 4 + reg][c] = t1[reg];
            }
        }
    }
    __syncthreads();

    __shared__ float sPer[32];
    if (tid < 32) {
        const int i = ib * 32 + tid;        // (tid>>4)*16 + (tid&15) == tid
        float a11[11];
#pragma unroll
        for (int cc = 0; cc < 11; ++cc) a11[cc] = sC[tid >> 4][tid & 15][cc];

        // self-kernel: reconstruct the SAME bf16 operand values as the pack,
        // sum products in fixed order, exp2 + bf16-round like the PV input.
        const float* f = &P[(size_t)i * 12];
        float FH[10], FL[10], LH[10], LL[10];
#pragma unroll
        for (int cc = 0; cc < 10; ++cc) {
            u16 a = f2bf(f[cc]);           FH[cc] = bf2f(a);
            u16 b = f2bf(f[cc] - FH[cc]);  FL[cc] = bf2f(b);
            float L = L10[(size_t)i * NC + cc];
            u16 x = f2bf(L);               LH[cc] = bf2f(x);
            u16 y = f2bf(L - LH[cc]);      LL[cc] = bf2f(y);
        }
        float nb2 = f[10];
        float BH = bf2f(f2bf(nb2));
        float BL = bf2f(f2bf(nb2 - BH));
        float S = 0.f;
#pragma unroll
        for (int cc = 0; cc < 10; ++cc) S += FH[cc] * LH[cc];
#pragma unroll
        for (int cc = 0; cc < 10; ++cc) S += FL[cc] * LH[cc];
#pragma unroll
        for (int cc = 0; cc < 10; ++cc) S += FH[cc] * LL[cc];
        S += BH; S += BL;
        float self = bf2f((u16)(cvtpk_bf16(EXP2F(S), 0.f) & 0xFFFFu));
        int lab = __float_as_int(f[11]);
        float den = a11[10] - self;
        switch (lab) {
#define CASE(cc) case cc: a11[cc] -= self; break;
            CASE(0) CASE(1) CASE(2) CASE(3) CASE(4)
            CASE(5) CASE(6) CASE(7) CASE(8) CASE(9)
#undef CASE
        }

        den = fmaxf(den, 1e-10f);   // clip(den, EPS_DEN, None)
        float per = 0.f;
#pragma unroll
        for (int cc = 0; cc < NC; ++cc) per += fabsf(a11[cc] / den - f[cc]);
        sPer[tid] = per;
    }
    __syncthreads();
    if (tid == 0) {
        float s = 0.f;
#pragma unroll
        for (int k = 0; k < 32; ++k) s += sPer[k];
        // one f32 atomic per block (256 total). Ordering wobble ~1e-7 rel —
        // 5 orders below the 1.4e-2 threshold. out zeroed by memset node.
        atomicAdd(out, s * (1.0f / NROWS));
    }
}

extern "C" void kernel_launch(void* const* d_in, const int* in_sizes, int n_in,
                              void* d_out, int out_size, void* d_ws, size_t ws_size,
                              hipStream_t stream) {
    const float* logits = (const float*)d_in[0];
    const int* labels = (const int*)d_in[1];
    float* out = (float*)d_out;
    float* ws = (float*)d_ws;

    float* P   = ws;                                   // 12N
    float* L10 = ws + 12 * NROWS;                      // 10N
    u16* AFP = (u16*)(ws + 22 * NROWS);                // 16N f32-equiv
    u16* BLP = (u16*)(ws + 38 * NROWS);                // 16N
    u16* OHP = (u16*)(ws + 54 * NROWS);                // 8N

    hipMemsetAsync(out, 0, sizeof(float), stream);     // graph-capturable node
    kde_prep_pack<<<dim3(NROWS / 64), dim3(64), 0, stream>>>(logits, labels, P, L10,
                                                             AFP, BLP, OHP);
    kde_main<<<dim3(256), dim3(1024), 0, stream>>>(AFP, BLP, OHP, P, L10, out);
}

// Round 16
// 28.387 us; speedup vs baseline: 1.1416x; 1.0541x over previous
//
#include <hip/hip_runtime.h>
#include <math.h>

#define NROWS 8192
#define NC 10
#define LOG2E_F 1.4426950408889634f

typedef short bf16x8 __attribute__((ext_vector_type(8)));   // MFMA a/b frag
typedef float f32x4 __attribute__((ext_vector_type(4)));    // MFMA c/d frag
typedef unsigned short u16;
typedef unsigned int u32;

#if __has_builtin(__builtin_amdgcn_exp2f)
#define EXP2F(x) __builtin_amdgcn_exp2f(x)
#else
#define EXP2F(x) exp2f(x)
#endif

__device__ __forceinline__ float fast_log2(float x) {       // v_log_f32 = log2
    float r; asm("v_log_f32 %0, %1" : "=v"(r) : "v"(x)); return r;
}

// lgamma(x) for x in [1, 11.01]: Stirling at y=x+8 (2 correction terms)
// minus ln(x(x+1)...(x+7)). abs err < 1e-5 over the range.
__device__ __forceinline__ float lgamma_fast(float x) {
    const float LN2 = 0.6931471805599453f;
    float p = x * (x + 1.f) * (x + 2.f) * (x + 3.f) *
              (x + 4.f) * (x + 5.f) * (x + 6.f) * (x + 7.f);
    float y = x + 8.f;
    float lny = fast_log2(y) * LN2;
    float lnp = fast_log2(p) * LN2;
    float r = 1.f / y;
    return fmaf(y - 0.5f, lny, -y) + 0.91893853320467274f   // 0.5*ln(2*pi)
           + r * (1.f / 12.f) - (r * r * r) * (1.f / 360.f) - lnp;
}

__device__ __forceinline__ u16 f2bf(float x) {              // RNE f32->bf16
    u32 u = __float_as_uint(x);
    return (u16)((u + 0x7FFFu + ((u >> 16) & 1u)) >> 16);
}
__device__ __forceinline__ float bf2f(u16 b) { return __uint_as_float(((u32)b) << 16); }
__device__ __forceinline__ u32 cvtpk_bf16(float lo, float hi) {
    u32 r; asm("v_cvt_pk_bf16_f32 %0, %1, %2" : "=v"(r) : "v"(lo), "v"(hi)); return r;
}

union U8 { u16 s[8]; int4 v; };

// ws layout (f32 units):
//   P    : [N][12] = {f0..f9, -B2, label_bits}      0   .. 12N
//   L10  : [N][10]                                  12N .. 22N
//   AFP  : [512 jt16][64][8] bf16                   22N .. 38N
//   BLP  : [512 it16][64][8] bf16                   38N .. 54N
//   OHP  : [256 jt32][64][8] bf16                   54N .. 62N
//   acc  : f32 at 62N ; cnt : u32 at 62N+1

// ---------------- Kernel 1: prep + pack (128 blocks x 64 threads) -----------
// (round-13 verbatim + accumulator zeroing)
__global__ __launch_bounds__(64) void kde_prep_pack(const float* __restrict__ logits,
                                                    const int* __restrict__ labels,
                                                    float* __restrict__ P,
                                                    float* __restrict__ L10,
                                                    u16* __restrict__ AFP,
                                                    u16* __restrict__ BLP,
                                                    u16* __restrict__ OHP,
                                                    float* __restrict__ accv) {
    __shared__ float sF[64][NC];
    __shared__ float sL[64][NC];
    __shared__ float sB2[64];
    __shared__ int sLab[64];
    const int tid = threadIdx.x, bx = blockIdx.x;
    const int i = bx * 64 + tid;

    if (bx == 0 && tid == 0) {          // re-zero finish accumulators every call
        accv[0] = 0.f;
        ((u32*)accv)[1] = 0u;
    }

    float l[NC];
#pragma unroll
    for (int c = 0; c < NC; ++c) l[c] = logits[(size_t)i * NC + c];
    float m = l[0];
#pragma unroll
    for (int c = 1; c < NC; ++c) m = fmaxf(m, l[c]);
    float e[NC];
    float sum = 0.f;
#pragma unroll
    for (int c = 0; c < NC; ++c) {
        e[c] = EXP2F((l[c] - m) * LOG2E_F);
        sum += e[c];
    }
    float inv = 1.f / sum;
    float lg2sum = fast_log2(sum);
    float lg = 0.f;
#pragma unroll
    for (int c = 0; c < NC; ++c) {
        float f = e[c] * inv;
        P[(size_t)i * 12 + c] = f;
        sF[tid][c] = f;
        // L10 = 10*log2(f) analytically (f >= ~2e-4 here; eps irrelevant)
        float L = 10.f * ((l[c] - m) * LOG2E_F - lg2sum);
        L10[(size_t)i * NC + c] = L;
        sL[tid][c] = L;
        lg += lgamma_fast(fmaf(10.f, f, 1.f));
    }
    // sum(alphas) == 1/h + C == 20 exactly -> lgamma(20) = ln(19!) constant
    float b2 = (lg - 39.339884187199495f) * LOG2E_F;
    P[(size_t)i * 12 + 10] = -b2;
    sB2[tid] = -b2;
    int lab = labels[i];
    P[(size_t)i * 12 + 11] = __int_as_float(lab);
    sLab[tid] = lab;
    __syncthreads();

    const int lc = tid & 15, h = tid >> 4;
    // ---- AFP: 4 jt16 tiles (j side: Fhi/Flo, -B2 hi/lo) ----
#pragma unroll
    for (int t = 0; t < 4; ++t) {
        const int jl = t * 16 + lc;
        const float* f = sF[jl];
        u16 FH[10], FL[10];
#pragma unroll
        for (int c = 0; c < 10; ++c) {
            FH[c] = f2bf(f[c]);
            FL[c] = f2bf(f[c] - bf2f(FH[c]));
        }
        float nb2 = sB2[jl];
        u16 bh = f2bf(nb2);
        u16 blo = f2bf(nb2 - bf2f(bh));
        U8 o;
        if (h == 0) {        // k=0..7   : Fhi[0..7]
            o.s[0]=FH[0]; o.s[1]=FH[1]; o.s[2]=FH[2]; o.s[3]=FH[3];
            o.s[4]=FH[4]; o.s[5]=FH[5]; o.s[6]=FH[6]; o.s[7]=FH[7];
        } else if (h == 1) { // k=8..15 : Fhi[8,9], Flo[0..5]
            o.s[0]=FH[8]; o.s[1]=FH[9]; o.s[2]=FL[0]; o.s[3]=FL[1];
            o.s[4]=FL[2]; o.s[5]=FL[3]; o.s[6]=FL[4]; o.s[7]=FL[5];
        } else if (h == 2) { // k=16..23: Flo[6..9], Fhi[0..3]
            o.s[0]=FL[6]; o.s[1]=FL[7]; o.s[2]=FL[8]; o.s[3]=FL[9];
            o.s[4]=FH[0]; o.s[5]=FH[1]; o.s[6]=FH[2]; o.s[7]=FH[3];
        } else {             // k=24..31: Fhi[4..9], -B2hi, -B2lo
            o.s[0]=FH[4]; o.s[1]=FH[5]; o.s[2]=FH[6]; o.s[3]=FH[7];
            o.s[4]=FH[8]; o.s[5]=FH[9]; o.s[6]=bh;    o.s[7]=blo;
        }
        *(int4*)&AFP[((size_t)(bx * 4 + t) * 64 + tid) * 8] = o.v;
    }
    // ---- BLP: 4 it16 tiles (i side: L10hi/lo, ones) ----
#pragma unroll
    for (int t = 0; t < 4; ++t) {
        const int il = t * 16 + lc;
        u16 LH[10], LL[10];
#pragma unroll
        for (int c = 0; c < 10; ++c) {
            float L = sL[il][c];
            LH[c] = f2bf(L);
            LL[c] = f2bf(L - bf2f(LH[c]));
        }
        const u16 ONE = 0x3F80;
        U8 o;
        if (h == 0) {        // k=0..7   : L10hi[0..7]
            o.s[0]=LH[0]; o.s[1]=LH[1]; o.s[2]=LH[2]; o.s[3]=LH[3];
            o.s[4]=LH[4]; o.s[5]=LH[5]; o.s[6]=LH[6]; o.s[7]=LH[7];
        } else if (h == 1) { // k=8..15 : L10hi[8,9], L10hi[0..5]
            o.s[0]=LH[8]; o.s[1]=LH[9]; o.s[2]=LH[0]; o.s[3]=LH[1];
            o.s[4]=LH[2]; o.s[5]=LH[3]; o.s[6]=LH[4]; o.s[7]=LH[5];
        } else if (h == 2) { // k=16..23: L10hi[6..9], L10lo[0..3]
            o.s[0]=LH[6]; o.s[1]=LH[7]; o.s[2]=LH[8]; o.s[3]=LH[9];
            o.s[4]=LL[0]; o.s[5]=LL[1]; o.s[6]=LL[2]; o.s[7]=LL[3];
        } else {             // k=24..31: L10lo[4..9], 1, 1
            o.s[0]=LL[4]; o.s[1]=LL[5]; o.s[2]=LL[6]; o.s[3]=LL[7];
            o.s[4]=LL[8]; o.s[5]=LL[9]; o.s[6]=ONE;   o.s[7]=ONE;
        }
        *(int4*)&BLP[((size_t)(bx * 4 + t) * 64 + tid) * 8] = o.v;
    }
    // ---- OHP: 2 jt32 tiles (onehot + den-ones col 10) ----
#pragma unroll
    for (int t = 0; t < 2; ++t) {
        U8 o;
#pragma unroll
        for (int e = 0; e < 8; ++e) {
            int jl = t * 32 + ((e >> 2) << 4) + h * 4 + (e & 3);   // j_log(h,e)
            int lj = sLab[jl];
            o.s[e] = (lc == lj || lc == 10) ? (u16)0x3F80 : (u16)0;
        }
        *(int4*)&OHP[((size_t)(bx * 2 + t) * 64 + tid) * 8] = o.v;
    }
}

// ---- Kernel 2: MFMA main (256 x 1024) + fence-free last-block finish -------
__global__ __launch_bounds__(1024) void kde_main(const u16* __restrict__ AFP_,
                                                 const u16* __restrict__ BLP_,
                                                 const u16* __restrict__ OHP_,
                                                 const float* __restrict__ P,
                                                 const float* __restrict__ L10,
                                                 float* accv,
                                                 float* __restrict__ out) {
    const bf16x8* AFP = (const bf16x8*)AFP_;
    const bf16x8* BLP = (const bf16x8*)BLP_;
    const bf16x8* OHP = (const bf16x8*)OHP_;
    const int tid = threadIdx.x, w = tid >> 6, l = tid & 63;   // 16 waves
    const int ib = blockIdx.x;          // 32 i-rows per block: i = ib*32 + [0,32)

    bf16x8 bl[2];                       // block's 2 it16 B-frags (same for all waves)
#pragma unroll
    for (int t = 0; t < 2; ++t) bl[t] = BLP[(size_t)(ib * 2 + t) * 64 + l];

    const f32x4 z = {0.f, 0.f, 0.f, 0.f};
    f32x4 acc[2] = {z, z};

    // wave w covers jt in [w*16, w*16+16) -> 16 waves cover all 256 jt32 tiles
    for (int jt = w * 16; jt < w * 16 + 16; ++jt) {
        bf16x8 af0 = AFP[(size_t)(2 * jt) * 64 + l];
        bf16x8 af1 = AFP[(size_t)(2 * jt + 1) * 64 + l];
        bf16x8 oh  = OHP[(size_t)jt * 64 + l];
#pragma unroll
        for (int t = 0; t < 2; ++t) {
            f32x4 s0 = __builtin_amdgcn_mfma_f32_16x16x32_bf16(af0, bl[t], z, 0, 0, 0);
            f32x4 s1 = __builtin_amdgcn_mfma_f32_16x16x32_bf16(af1, bl[t], z, 0, 0, 0);
            union { bf16x8 v; u32 u[4]; } kf;
            kf.u[0] = cvtpk_bf16(EXP2F(s0.x), EXP2F(s0.y));
            kf.u[1] = cvtpk_bf16(EXP2F(s0.z), EXP2F(s0.w));
            kf.u[2] = cvtpk_bf16(EXP2F(s1.x), EXP2F(s1.y));
            kf.u[3] = cvtpk_bf16(EXP2F(s1.z), EXP2F(s1.w));
            acc[t] = __builtin_amdgcn_mfma_f32_16x16x32_bf16(kf.v, oh, acc[t], 0, 0, 0);
        }
    }

    // ---- cross-wave reduction (w-ascending = j-ascending left fold) ----
    __shared__ f32x4 sRed[16][2][64];   // 32 KB
    sRed[w][0][l] = acc[0];
    sRed[w][1][l] = acc[1];
    __syncthreads();

    __shared__ float sC[2][16][12];     // [tile][row][class] (pad 12)
    if (w == 0) {
        f32x4 t0 = sRed[0][0][l];
        f32x4 t1 = sRed[0][1][l];
#pragma unroll
        for (int ww = 1; ww < 16; ++ww) { t0 += sRed[ww][0][l]; t1 += sRed[ww][1][l]; }
        const int c = l & 15, h = l >> 4;   // verified C/D map: col=lane&15, row=(lane>>4)*4+reg
        if (c < 11) {
#pragma unroll
            for (int reg = 0; reg < 4; ++reg) {
                sC[0][h * 4 + reg][c] = t0[reg];
                sC[1][h * 4 + reg][c] = t1[reg];
            }
        }
    }
    __syncthreads();

    __shared__ float sPer[32];
    if (tid < 32) {
        const int i = ib * 32 + tid;        // (tid>>4)*16 + (tid&15) == tid
        float a11[11];
#pragma unroll
        for (int cc = 0; cc < 11; ++cc) a11[cc] = sC[tid >> 4][tid & 15][cc];

        // self-kernel: reconstruct the SAME bf16 operand values as the pack,
        // sum products in fixed order, exp2 + bf16-round like the PV input.
        const float* f = &P[(size_t)i * 12];
        float FH[10], FL[10], LH[10], LL[10];
#pragma unroll
        for (int cc = 0; cc < 10; ++cc) {
            u16 a = f2bf(f[cc]);           FH[cc] = bf2f(a);
            u16 b = f2bf(f[cc] - FH[cc]);  FL[cc] = bf2f(b);
            float L = L10[(size_t)i * NC + cc];
            u16 x = f2bf(L);               LH[cc] = bf2f(x);
            u16 y = f2bf(L - LH[cc]);      LL[cc] = bf2f(y);
        }
        float nb2 = f[10];
        float BH = bf2f(f2bf(nb2));
        float BL = bf2f(f2bf(nb2 - BH));
        float S = 0.f;
#pragma unroll
        for (int cc = 0; cc < 10; ++cc) S += FH[cc] * LH[cc];
#pragma unroll
        for (int cc = 0; cc < 10; ++cc) S += FL[cc] * LH[cc];
#pragma unroll
        for (int cc = 0; cc < 10; ++cc) S += FH[cc] * LL[cc];
        S += BH; S += BL;
        float self = bf2f((u16)(cvtpk_bf16(EXP2F(S), 0.f) & 0xFFFFu));
        int lab = __float_as_int(f[11]);
        float den = a11[10] - self;
        switch (lab) {
#define CASE(cc) case cc: a11[cc] -= self; break;
            CASE(0) CASE(1) CASE(2) CASE(3) CASE(4)
            CASE(5) CASE(6) CASE(7) CASE(8) CASE(9)
#undef CASE
        }

        den = fmaxf(den, 1e-10f);   // clip(den, EPS_DEN, None)
        float per = 0.f;
#pragma unroll
        for (int cc = 0; cc < NC; ++cc) per += fabsf(a11[cc] / den - f[cc]);
        sPer[tid] = per;
    }
    __syncthreads();
    if (tid == 0) {
        float s = 0.f;
#pragma unroll
        for (int k = 0; k < 32; ++k) s += sPer[k];
        // fence-free finish: value-add (ack'd), then ticket; last ticket holder
        // atomically reads the full total and plain-stores out[0].
        float old = atomicAdd(accv, s * (1.0f / NROWS));
        asm volatile("" :: "v"(old));              // keep ack'd return live
        u32 c = atomicAdd((u32*)accv + 1, 1u);
        if (c == 255u) {
            float total = atomicAdd(accv, 0.0f);   // serialized after all adds
            out[0] = total;
        }
    }
}

extern "C" void kernel_launch(void* const* d_in, const int* in_sizes, int n_in,
                              void* d_out, int out_size, void* d_ws, size_t ws_size,
                              hipStream_t stream) {
    const float* logits = (const float*)d_in[0];
    const int* labels = (const int*)d_in[1];
    float* out = (float*)d_out;
    float* ws = (float*)d_ws;

    float* P   = ws;                                   // 12N
    float* L10 = ws + 12 * NROWS;                      // 10N
    u16* AFP = (u16*)(ws + 22 * NROWS);                // 16N f32-equiv
    u16* BLP = (u16*)(ws + 38 * NROWS);                // 16N
    u16* OHP = (u16*)(ws + 54 * NROWS);                // 8N
    float* accv = ws + 62 * NROWS;                     // {acc f32, cnt u32}

    kde_prep_pack<<<dim3(NROWS / 64), dim3(64), 0, stream>>>(logits, labels, P, L10,
                                                             AFP, BLP, OHP, accv);
    kde_main<<<dim3(256), dim3(1024), 0, stream>>>(AFP, BLP, OHP, P, L10, accv, out);
}

// Round 17
// 23.909 us; speedup vs baseline: 1.3554x; 1.1873x over previous
//
#include <hip/hip_runtime.h>
#include <math.h>

#define NROWS 8192
#define NC 10
#define LOG2E_F 1.4426950408889634f

typedef short bf16x8 __attribute__((ext_vector_type(8)));   // MFMA a/b frag
typedef float f32x4 __attribute__((ext_vector_type(4)));    // MFMA c/d frag
typedef unsigned short u16;
typedef unsigned int u32;

#if __has_builtin(__builtin_amdgcn_exp2f)
#define EXP2F(x) __builtin_amdgcn_exp2f(x)
#else
#define EXP2F(x) exp2f(x)
#endif

__device__ __forceinline__ float fast_log2(float x) {       // v_log_f32 = log2
    float r; asm("v_log_f32 %0, %1" : "=v"(r) : "v"(x)); return r;
}

// lgamma(x) for x in [1, 11.01]: Stirling at y=x+8 (2 correction terms)
// minus ln(x(x+1)...(x+7)). abs err < 1e-5 over the range.
__device__ __forceinline__ float lgamma_fast(float x) {
    const float LN2 = 0.6931471805599453f;
    float p = x * (x + 1.f) * (x + 2.f) * (x + 3.f) *
              (x + 4.f) * (x + 5.f) * (x + 6.f) * (x + 7.f);
    float y = x + 8.f;
    float lny = fast_log2(y) * LN2;
    float lnp = fast_log2(p) * LN2;
    float r = 1.f / y;
    return fmaf(y - 0.5f, lny, -y) + 0.91893853320467274f   // 0.5*ln(2*pi)
           + r * (1.f / 12.f) - (r * r * r) * (1.f / 360.f) - lnp;
}

__device__ __forceinline__ u16 f2bf(float x) {              // RNE f32->bf16
    u32 u = __float_as_uint(x);
    return (u16)((u + 0x7FFFu + ((u >> 16) & 1u)) >> 16);
}
__device__ __forceinline__ float bf2f(u16 b) { return __uint_as_float(((u32)b) << 16); }
__device__ __forceinline__ u32 cvtpk_bf16(float lo, float hi) {
    u32 r; asm("v_cvt_pk_bf16_f32 %0, %1, %2" : "=v"(r) : "v"(lo), "v"(hi)); return r;
}

union U8 { u16 s[8]; int4 v; };

// ws layout (f32 units):
//   P    : [N][12] = {f0..f9, -B2, label_bits}      0   .. 12N
//   L10  : [N][10]                                  12N .. 22N
//   AFP  : [512 jt16][64][8] bf16                   22N .. 38N
//   BLP  : [512 it16][64][8] bf16                   38N .. 54N
//   OHP  : [256 jt32][64][8] bf16                   54N .. 62N
//   bsum : [256]                                    62N

// ---------------- Kernel 1: prep + pack (128 blocks x 64 threads) -----------
__global__ __launch_bounds__(64) void kde_prep_pack(const float* __restrict__ logits,
                                                    const int* __restrict__ labels,
                                                    float* __restrict__ P,
                                                    float* __restrict__ L10,
                                                    u16* __restrict__ AFP,
                                                    u16* __restrict__ BLP,
                                                    u16* __restrict__ OHP) {
    __shared__ float sF[64][NC];
    __shared__ float sL[64][NC];
    __shared__ float sB2[64];
    __shared__ int sLab[64];
    const int tid = threadIdx.x, bx = blockIdx.x;
    const int i = bx * 64 + tid;

    float l[NC];
#pragma unroll
    for (int c = 0; c < NC; ++c) l[c] = logits[(size_t)i * NC + c];
    float m = l[0];
#pragma unroll
    for (int c = 1; c < NC; ++c) m = fmaxf(m, l[c]);
    float e[NC];
    float sum = 0.f;
#pragma unroll
    for (int c = 0; c < NC; ++c) {
        e[c] = EXP2F((l[c] - m) * LOG2E_F);
        sum += e[c];
    }
    float inv = 1.f / sum;
    float lg2sum = fast_log2(sum);
    float lg = 0.f;
#pragma unroll
    for (int c = 0; c < NC; ++c) {
        float f = e[c] * inv;
        P[(size_t)i * 12 + c] = f;
        sF[tid][c] = f;
        // L10 = 10*log2(f) analytically (f >= ~2e-4 here; eps irrelevant)
        float L = 10.f * ((l[c] - m) * LOG2E_F - lg2sum);
        L10[(size_t)i * NC + c] = L;
        sL[tid][c] = L;
        lg += lgamma_fast(fmaf(10.f, f, 1.f));
    }
    // sum(alphas) == 1/h + C == 20 exactly -> lgamma(20) = ln(19!) constant
    float b2 = (lg - 39.339884187199495f) * LOG2E_F;
    P[(size_t)i * 12 + 10] = -b2;
    sB2[tid] = -b2;
    int lab = labels[i];
    P[(size_t)i * 12 + 11] = __int_as_float(lab);
    sLab[tid] = lab;
    __syncthreads();

    const int lc = tid & 15, h = tid >> 4;
    // ---- AFP: 4 jt16 tiles (j side: Fhi/Flo, -B2 hi/lo) ----
#pragma unroll
    for (int t = 0; t < 4; ++t) {
        const int jl = t * 16 + lc;
        const float* f = sF[jl];
        u16 FH[10], FL[10];
#pragma unroll
        for (int c = 0; c < 10; ++c) {
            FH[c] = f2bf(f[c]);
            FL[c] = f2bf(f[c] - bf2f(FH[c]));
        }
        float nb2 = sB2[jl];
        u16 bh = f2bf(nb2);
        u16 blo = f2bf(nb2 - bf2f(bh));
        U8 o;
        if (h == 0) {        // k=0..7   : Fhi[0..7]
            o.s[0]=FH[0]; o.s[1]=FH[1]; o.s[2]=FH[2]; o.s[3]=FH[3];
            o.s[4]=FH[4]; o.s[5]=FH[5]; o.s[6]=FH[6]; o.s[7]=FH[7];
        } else if (h == 1) { // k=8..15 : Fhi[8,9], Flo[0..5]
            o.s[0]=FH[8]; o.s[1]=FH[9]; o.s[2]=FL[0]; o.s[3]=FL[1];
            o.s[4]=FL[2]; o.s[5]=FL[3]; o.s[6]=FL[4]; o.s[7]=FL[5];
        } else if (h == 2) { // k=16..23: Flo[6..9], Fhi[0..3]
            o.s[0]=FL[6]; o.s[1]=FL[7]; o.s[2]=FL[8]; o.s[3]=FL[9];
            o.s[4]=FH[0]; o.s[5]=FH[1]; o.s[6]=FH[2]; o.s[7]=FH[3];
        } else {             // k=24..31: Fhi[4..9], -B2hi, -B2lo
            o.s[0]=FH[4]; o.s[1]=FH[5]; o.s[2]=FH[6]; o.s[3]=FH[7];
            o.s[4]=FH[8]; o.s[5]=FH[9]; o.s[6]=bh;    o.s[7]=blo;
        }
        *(int4*)&AFP[((size_t)(bx * 4 + t) * 64 + tid) * 8] = o.v;
    }
    // ---- BLP: 4 it16 tiles (i side: L10hi/lo, ones) ----
#pragma unroll
    for (int t = 0; t < 4; ++t) {
        const int il = t * 16 + lc;
        u16 LH[10], LL[10];
#pragma unroll
        for (int c = 0; c < 10; ++c) {
            float L = sL[il][c];
            LH[c] = f2bf(L);
            LL[c] = f2bf(L - bf2f(LH[c]));
        }
        const u16 ONE = 0x3F80;
        U8 o;
        if (h == 0) {        // k=0..7   : L10hi[0..7]
            o.s[0]=LH[0]; o.s[1]=LH[1]; o.s[2]=LH[2]; o.s[3]=LH[3];
            o.s[4]=LH[4]; o.s[5]=LH[5]; o.s[6]=LH[6]; o.s[7]=LH[7];
        } else if (h == 1) { // k=8..15 : L10hi[8,9], L10hi[0..5]
            o.s[0]=LH[8]; o.s[1]=LH[9]; o.s[2]=LH[0]; o.s[3]=LH[1];
            o.s[4]=LH[2]; o.s[5]=LH[3]; o.s[6]=LH[4]; o.s[7]=LH[5];
        } else if (h == 2) { // k=16..23: L10hi[6..9], L10lo[0..3]
            o.s[0]=LH[6]; o.s[1]=LH[7]; o.s[2]=LH[8]; o.s[3]=LH[9];
            o.s[4]=LL[0]; o.s[5]=LL[1]; o.s[6]=LL[2]; o.s[7]=LL[3];
        } else {             // k=24..31: L10lo[4..9], 1, 1
            o.s[0]=LL[4]; o.s[1]=LL[5]; o.s[2]=LL[6]; o.s[3]=LL[7];
            o.s[4]=LL[8]; o.s[5]=LL[9]; o.s[6]=ONE;   o.s[7]=ONE;
        }
        *(int4*)&BLP[((size_t)(bx * 4 + t) * 64 + tid) * 8] = o.v;
    }
    // ---- OHP: 2 jt32 tiles (onehot + den-ones col 10) ----
#pragma unroll
    for (int t = 0; t < 2; ++t) {
        U8 o;
#pragma unroll
        for (int e = 0; e < 8; ++e) {
            int jl = t * 32 + ((e >> 2) << 4) + h * 4 + (e & 3);   // j_log(h,e)
            int lj = sLab[jl];
            o.s[e] = (lc == lj || lc == 10) ? (u16)0x3F80 : (u16)0;
        }
        *(int4*)&OHP[((size_t)(bx * 2 + t) * 64 + tid) * 8] = o.v;
    }
}

// ---- Kernel 2: MFMA main, full-j per block + in-block finish (256 x 1024) ---
__global__ __launch_bounds__(1024) void kde_main(const u16* __restrict__ AFP_,
                                                 const u16* __restrict__ BLP_,
                                                 const u16* __restrict__ OHP_,
                                                 const float* __restrict__ P,
                                                 const float* __restrict__ L10,
                                                 float* __restrict__ bsum) {
    const bf16x8* AFP = (const bf16x8*)AFP_;
    const bf16x8* BLP = (const bf16x8*)BLP_;
    const bf16x8* OHP = (const bf16x8*)OHP_;
    const int tid = threadIdx.x, w = tid >> 6, l = tid & 63;   // 16 waves
    const int ib = blockIdx.x;          // 32 i-rows per block: i = ib*32 + [0,32)

    bf16x8 bl[2];                       // block's 2 it16 B-frags (same for all waves)
#pragma unroll
    for (int t = 0; t < 2; ++t) bl[t] = BLP[(size_t)(ib * 2 + t) * 64 + l];

    const f32x4 z = {0.f, 0.f, 0.f, 0.f};
    f32x4 acc[2] = {z, z};

    // wave w covers jt in [w*16, w*16+16) -> 16 waves cover all 256 jt32 tiles
    for (int jt = w * 16; jt < w * 16 + 16; ++jt) {
        bf16x8 af0 = AFP[(size_t)(2 * jt) * 64 + l];
        bf16x8 af1 = AFP[(size_t)(2 * jt + 1) * 64 + l];
        bf16x8 oh  = OHP[(size_t)jt * 64 + l];
#pragma unroll
        for (int t = 0; t < 2; ++t) {
            f32x4 s0 = __builtin_amdgcn_mfma_f32_16x16x32_bf16(af0, bl[t], z, 0, 0, 0);
            f32x4 s1 = __builtin_amdgcn_mfma_f32_16x16x32_bf16(af1, bl[t], z, 0, 0, 0);
            union { bf16x8 v; u32 u[4]; } kf;
            kf.u[0] = cvtpk_bf16(EXP2F(s0.x), EXP2F(s0.y));
            kf.u[1] = cvtpk_bf16(EXP2F(s0.z), EXP2F(s0.w));
            kf.u[2] = cvtpk_bf16(EXP2F(s1.x), EXP2F(s1.y));
            kf.u[3] = cvtpk_bf16(EXP2F(s1.z), EXP2F(s1.w));
            acc[t] = __builtin_amdgcn_mfma_f32_16x16x32_bf16(kf.v, oh, acc[t], 0, 0, 0);
        }
    }

    // ---- cross-wave reduction (w-ascending = j-ascending left fold) ----
    __shared__ f32x4 sRed[16][2][64];   // 32 KB
    sRed[w][0][l] = acc[0];
    sRed[w][1][l] = acc[1];
    __syncthreads();

    __shared__ float sC[2][16][12];     // [tile][row][class] (pad 12)
    if (w == 0) {
        f32x4 t0 = sRed[0][0][l];
        f32x4 t1 = sRed[0][1][l];
#pragma unroll
        for (int ww = 1; ww < 16; ++ww) { t0 += sRed[ww][0][l]; t1 += sRed[ww][1][l]; }
        const int c = l & 15, h = l >> 4;   // verified C/D map: col=lane&15, row=(lane>>4)*4+reg
        if (c < 11) {
#pragma unroll
            for (int reg = 0; reg < 4; ++reg) {
                sC[0][h * 4 + reg][c] = t0[reg];
                sC[1][h * 4 + reg][c] = t1[reg];
            }
        }
    }
    __syncthreads();

    __shared__ float sPer[32];
    if (tid < 32) {
        const int i = ib * 32 + tid;        // (tid>>4)*16 + (tid&15) == tid
        float a11[11];
#pragma unroll
        for (int cc = 0; cc < 11; ++cc) a11[cc] = sC[tid >> 4][tid & 15][cc];

        // self-kernel: reconstruct the SAME bf16 operand values as the pack,
        // sum products in fixed order, exp2 + bf16-round like the PV input.
        const float* f = &P[(size_t)i * 12];
        float FH[10], FL[10], LH[10], LL[10];
#pragma unroll
        for (int cc = 0; cc < 10; ++cc) {
            u16 a = f2bf(f[cc]);           FH[cc] = bf2f(a);
            u16 b = f2bf(f[cc] - FH[cc]);  FL[cc] = bf2f(b);
            float L = L10[(size_t)i * NC + cc];
            u16 x = f2bf(L);               LH[cc] = bf2f(x);
            u16 y = f2bf(L - LH[cc]);      LL[cc] = bf2f(y);
        }
        float nb2 = f[10];
        float BH = bf2f(f2bf(nb2));
        float BL = bf2f(f2bf(nb2 - BH));
        float S = 0.f;
#pragma unroll
        for (int cc = 0; cc < 10; ++cc) S += FH[cc] * LH[cc];
#pragma unroll
        for (int cc = 0; cc < 10; ++cc) S += FL[cc] * LH[cc];
#pragma unroll
        for (int cc = 0; cc < 10; ++cc) S += FH[cc] * LL[cc];
        S += BH; S += BL;
        float self = bf2f((u16)(cvtpk_bf16(EXP2F(S), 0.f) & 0xFFFFu));
        int lab = __float_as_int(f[11]);
        float den = a11[10] - self;
        switch (lab) {
#define CASE(cc) case cc: a11[cc] -= self; break;
            CASE(0) CASE(1) CASE(2) CASE(3) CASE(4)
            CASE(5) CASE(6) CASE(7) CASE(8) CASE(9)
#undef CASE
        }

        den = fmaxf(den, 1e-10f);   // clip(den, EPS_DEN, None)
        float per = 0.f;
#pragma unroll
        for (int cc = 0; cc < NC; ++cc) per += fabsf(a11[cc] / den - f[cc]);
        sPer[tid] = per;
    }
    __syncthreads();
    if (tid == 0) {
        float s = 0.f;
#pragma unroll
        for (int k = 0; k < 32; ++k) s += sPer[k];
        bsum[ib] = s;
    }
}

// ---------------- Kernel 3: final 256-value reduce (1 block) ----------------
__global__ __launch_bounds__(256) void kde_finC(const float* __restrict__ bsum,
                                                float* __restrict__ out) {
    __shared__ float red[256];
    const int t = threadIdx.x;
    red[t] = bsum[t];
    __syncthreads();
    for (int off = 128; off > 0; off >>= 1) {
        if (t < off) red[t] += red[t + off];
        __syncthreads();
    }
    if (t == 0) out[0] = red[0] * (1.0f / NROWS);
}

extern "C" void kernel_launch(void* const* d_in, const int* in_sizes, int n_in,
                              void* d_out, int out_size, void* d_ws, size_t ws_size,
                              hipStream_t stream) {
    const float* logits = (const float*)d_in[0];
    const int* labels = (const int*)d_in[1];
    float* out = (float*)d_out;
    float* ws = (float*)d_ws;

    float* P   = ws;                                   // 12N
    float* L10 = ws + 12 * NROWS;                      // 10N
    u16* AFP = (u16*)(ws + 22 * NROWS);                // 16N f32-equiv
    u16* BLP = (u16*)(ws + 38 * NROWS);                // 16N
    u16* OHP = (u16*)(ws + 54 * NROWS);                // 8N
    float* bsum = ws + 62 * NROWS;                     // 256

    kde_prep_pack<<<dim3(NROWS / 64), dim3(64), 0, stream>>>(logits, labels, P, L10,
                                                             AFP, BLP, OHP);
    kde_main<<<dim3(256), dim3(1024), 0, stream>>>(AFP, BLP, OHP, P, L10, bsum);
    kde_finC<<<dim3(1), dim3(256), 0, stream>>>(bsum, out);
}